// Round 18
// baseline (178.055 us; speedup 1.0000x reference)
//
#include <hip/hip_runtime.h>

#define BB 64
#define TT 2048
#define DD 512
#define UU 32

// Speculation geometry: NSEG segments of SEGLEN rows; junction j (1..NJ) at
// row SEGLEN*j+1. Chained-parallel scans (R14/R16-verified algebra):
//   C[0]=0, C[j]=C[j-1]+c'_j; rows [jr_j, ts_j] hold true-C[j-1], rows
//   (ts_j, E_j] hold spec = true-C[j]. Offsets applied at read time in k3/k4.
#define NSEG 16
#define SEGLEN 128            // TT/NSEG
#define SEGSH 7               // log2(SEGLEN)
#define NJ (NSEG - 1)
#define WSAVE 96              // logit rows saved per junction for fast scans

__device__ int g_ts[BB * NJ];
__device__ float g_c[BB * NJ];
__device__ float g_bound[BB * NSEG * 64];
// saved logit columns (per-lane tgtS value) for rows jr+1..jr+WSAVE of each
// junction's segment — lets k2b step the TRUE chain with ONE tree (verified
// K2_FSTEP) instead of the two-tree transport, halving scan cost.  23.6 MB.
__device__ float g_slog[(size_t)BB * NJ * WSAVE * 64];

// ---------------------------------------------------------------------------
// K1: logits GEMM (R15-verified: 256-row geometry + k-pair x-reads).
// ---------------------------------------------------------------------------
__global__ __launch_bounds__(256) void k1_logits(const float* __restrict__ x,
                                                 const float* __restrict__ w,
                                                 const float* __restrict__ bias,
                                                 float* __restrict__ out) {
  __shared__ float xs[256 * 34];
  __shared__ float wsh[32 * 36];
  const int tid = threadIdx.x;
  const long row0 = (long)blockIdx.x * 256;
  const int tr = tid >> 2;
  const int tc = tid & 3;
  const int ubase = tc * 8;
  const int sr = tid >> 3;
  const int sc = (tid & 7) * 4;

  float acc[4][8];
#pragma unroll
  for (int i = 0; i < 4; ++i)
#pragma unroll
    for (int j = 0; j < 8; ++j) acc[i][j] = 0.0f;

  for (int kc = 0; kc < DD; kc += 32) {
#pragma unroll
    for (int p = 0; p < 8; ++p) {
      const int r = p * 32 + sr;
      const float4 v = *(const float4*)(x + (row0 + r) * DD + kc + sc);
      *(float2*)(&xs[r * 34 + sc]) = make_float2(v.x, v.y);
      *(float2*)(&xs[r * 34 + sc + 2]) = make_float2(v.z, v.w);
    }
    {
      const int k = tid >> 3;
      const int uu4 = (tid & 7) * 4;
      const float4 v = *(const float4*)(w + (size_t)(kc + k) * UU + uu4);
      *(float4*)(&wsh[k * 36 + uu4]) = v;
    }
    __syncthreads();
#pragma unroll
    for (int kp = 0; kp < 16; ++kp) {
      const int k = kp * 2;
      const float4 wa0 = *(const float4*)(&wsh[k * 36 + ubase]);
      const float4 wa1 = *(const float4*)(&wsh[k * 36 + ubase + 4]);
      const float4 wb0 = *(const float4*)(&wsh[(k + 1) * 36 + ubase]);
      const float4 wb1 = *(const float4*)(&wsh[(k + 1) * 36 + ubase + 4]);
      const float wva[8] = {wa0.x, wa0.y, wa0.z, wa0.w, wa1.x, wa1.y, wa1.z, wa1.w};
      const float wvb[8] = {wb0.x, wb0.y, wb0.z, wb0.w, wb1.x, wb1.y, wb1.z, wb1.w};
#pragma unroll
      for (int i = 0; i < 4; ++i) {
        const float2 xv2 = *(const float2*)(&xs[(tr + 64 * i) * 34 + k]);
#pragma unroll
        for (int j = 0; j < 8; ++j) acc[i][j] = fmaf(xv2.x, wva[j], acc[i][j]);
#pragma unroll
        for (int j = 0; j < 8; ++j) acc[i][j] = fmaf(xv2.y, wvb[j], acc[i][j]);
      }
    }
    __syncthreads();
  }
  float bv[8];
#pragma unroll
  for (int j = 0; j < 8; ++j) bv[j] = bias[ubase + j];
#pragma unroll
  for (int i = 0; i < 4; ++i) {
    const long row = row0 + tr + 64 * i;
    float4 o0, o1;
    o0.x = acc[i][0] + bv[0]; o0.y = acc[i][1] + bv[1];
    o0.z = acc[i][2] + bv[2]; o0.w = acc[i][3] + bv[3];
    o1.x = acc[i][4] + bv[4]; o1.y = acc[i][5] + bv[5];
    o1.z = acc[i][6] + bv[6]; o1.w = acc[i][7] + bv[7];
    *(float4*)(out + row * UU + ubase) = o0;
    *(float4*)(out + row * UU + ubase + 4) = o1;
  }
}

// ======================= K2 common machinery (R7-verified) ==================

#define ROTF(S) \
  __int_as_float(__builtin_amdgcn_update_dpp(0, __float_as_int(P), 0x120 + (S), 0xF, 0xF, true))

#define K2_TREE                                                              \
    const float c0 = P + tvS[0];                                             \
    const float c1 = ROTF(1) + tvS[1];                                       \
    const float c2 = ROTF(2) + tvS[2];                                       \
    const float c3 = ROTF(3) + tvS[3];                                       \
    const float c4 = ROTF(4) + tvS[4];                                       \
    const float c5 = ROTF(5) + tvS[5];                                       \
    const float c6 = ROTF(6) + tvS[6];                                       \
    const float c7 = ROTF(7) + tvS[7];                                       \
    const float c8 = ROTF(8) + tvS[8];                                       \
    const float c9 = ROTF(9) + tvS[9];                                       \
    const float c10 = ROTF(10) + tvS[10];                                    \
    const float c11 = ROTF(11) + tvS[11];                                    \
    const float c12 = ROTF(12) + tvS[12];                                    \
    const float c13 = ROTF(13) + tvS[13];                                    \
    const float c14 = ROTF(14) + tvS[14];                                    \
    const float c15 = ROTF(15) + tvS[15];                                    \
    const float d0 = fmaxf(fmaxf(c0, c1), c2);                               \
    const float d1 = fmaxf(fmaxf(c3, c4), c5);                               \
    const float d2 = fmaxf(fmaxf(c6, c7), c8);                               \
    const float d3 = fmaxf(fmaxf(c9, c10), c11);                             \
    const float d4 = fmaxf(fmaxf(c12, c13), c14);                            \
    const float e0 = fmaxf(fmaxf(d0, d1), d2);                               \
    const float e1 = fmaxf(fmaxf(d3, d4), c15);                              \
    const float pm = fmaxf(e0, e1);

#if __has_builtin(__builtin_amdgcn_permlane32_swap) && __has_builtin(__builtin_amdgcn_permlane16_swap)
#define K2_HAVE_PERMLANE 1
typedef unsigned int v2u __attribute__((ext_vector_type(2)));

#define K2_FSTEP(tval, lg) do {                                              \
    K2_TREE                                                                  \
    v2u s32 = __builtin_amdgcn_permlane32_swap(__float_as_uint(pm),          \
                                               __float_as_uint(pm), false, false); \
    const float pd = fmaxf(__uint_as_float(s32.x), __uint_as_float(s32.y)) + (lg); \
    v2u s16 = __builtin_amdgcn_permlane16_swap(__float_as_uint(pd),          \
                                               __float_as_uint(pd), false, false); \
    const float cx = m16sel ? __uint_as_float(s16.x) : __uint_as_float(s16.y); \
    P = bit5v ? cx : pd;                                                     \
    base[(size_t)(tval) * UU + cstoS] = P;                                   \
  } while (0)

// combined pre-logit max (bitwise-identical tree + swap32 fold of K2_FSTEP)
__device__ __forceinline__ float k2_mcomb(float P, const float* tvS) {
  K2_TREE
  v2u s32 = __builtin_amdgcn_permlane32_swap(__float_as_uint(pm),
                                             __float_as_uint(pm), false, false);
  return fmaxf(__uint_as_float(s32.x), __uint_as_float(s32.y));
}

// generic segment runner: steps rows [A_,E_] with live P (clamped prefetch,
// no reads beyond E_ -> no cross-role races in k2a).
#define K2_RUNSEG(A_, E_) do {                                               \
    int tcc = (A_);                                                          \
    _Pragma("unroll")                                                        \
    for (int i = 0; i < 16; ++i) {                                           \
      int r = (A_) + i; if (r > (E_)) r = (E_);                              \
      bufA[i] = base[(size_t)r * UU + tgtS];                                 \
    }                                                                        \
    _Pragma("unroll 1")                                                      \
    for (; tcc + 31 <= (E_); tcc += 32) {                                    \
      _Pragma("unroll")                                                      \
      for (int i = 0; i < 16; ++i) bufB[i] = base[(size_t)(tcc + 16 + i) * UU + tgtS]; \
      _Pragma("unroll")                                                      \
      for (int i = 0; i < 16; ++i) K2_FSTEP(tcc + i, bufA[i]);               \
      _Pragma("unroll")                                                      \
      for (int i = 0; i < 16; ++i) {                                         \
        int r = tcc + 32 + i; if (r > (E_)) r = (E_);                        \
        bufA[i] = base[(size_t)r * UU + tgtS];                               \
      }                                                                      \
      _Pragma("unroll")                                                      \
      for (int i = 0; i < 16; ++i) K2_FSTEP(tcc + 16 + i, bufB[i]);          \
    }                                                                        \
    const int rem = (E_) - tcc + 1;                                          \
    if (rem > 0) {                                                           \
      _Pragma("unroll")                                                      \
      for (int i = 0; i < 16; ++i) {                                         \
        int r = tcc + 16 + i; if (r > (E_)) r = (E_);                        \
        bufB[i] = base[(size_t)r * UU + tgtS];                               \
      }                                                                      \
      _Pragma("unroll")                                                      \
      for (int i = 0; i < 16; ++i) { if (i < rem) K2_FSTEP(tcc + i, bufA[i]); } \
      _Pragma("unroll")                                                      \
      for (int i = 0; i < 16; ++i) { if (16 + i < rem) K2_FSTEP(tcc + 16 + i, bufB[i]); } \
    }                                                                        \
  } while (0)
#endif

// ---------------------------------------------------------------------------
// K2a: S=NSEG speculation. NSEG*64 blocks.
//  role 0: TRUE rows 1..SEGLEN; boundary vector -> g_bound slot 0.
//  role j: SPECULATIVE from fresh start at logits[SEGLEN*j+1]; while stepping
//  its first WSAVE rows it stashes the logit prefetch values (bufA/bufB hold
//  exactly logit[t][tgtS]) into g_slog so k2b can fast-scan; boundary vector
//  -> slot j.
// ---------------------------------------------------------------------------
__global__ __launch_bounds__(64) void k2a_forward(float* __restrict__ lb,
                                                  const float* __restrict__ trans) {
  const int lane = threadIdx.x;
  const int q = lane & 15;
  const int bit4 = (lane >> 4) & 1;
  const int bit5v = (lane >> 5) & 1;
  const int hiS = bit4 ^ bit5v;
  const int tgtS = bit4 * 16 + q;
  const int cstoS = hiS * 16 + q;
  const int role = blockIdx.x >> 6;
  const int b = blockIdx.x & 63;

  const int probe = __builtin_amdgcn_update_dpp(0, q, 0x121, 0xF, 0xF, false);
  const bool dirp = (probe == ((q + 1) & 15));

  float tvS[16];
#pragma unroll
  for (int s = 0; s < 16; ++s) {
    const int rp = dirp ? ((q + s) & 15) : ((q - s) & 15);
    tvS[s] = trans[(hiS * 16 + rp) * UU + tgtS];
  }

  float* base = lb + (size_t)b * TT * UU;
  float bufA[16], bufB[16];

#ifdef K2_HAVE_PERMLANE
  v2u p32 = __builtin_amdgcn_permlane32_swap((unsigned)lane, (unsigned)lane, false, false);
  v2u p16 = __builtin_amdgcn_permlane16_swap((unsigned)lane, (unsigned)lane, false, false);
  const bool c32ok = ((int)p32.x == (lane ^ 32)) || ((int)p32.y == (lane ^ 32));
  const bool c16ok = ((int)p16.x == (lane ^ 16)) || ((int)p16.y == (lane ^ 16));
  const bool m16sel = ((int)p16.x == (lane ^ 16));
  const bool okSwap = (__ballot(c32ok) == ~0ull) && (__ballot(c16ok) == ~0ull);

  if (okSwap) {
    if (role == 0) {
      float P = base[cstoS];
      K2_RUNSEG(1, SEGLEN);
      g_bound[((b << 4) + 0) * 64 + lane] = P;
    } else {
      const int s0 = SEGLEN * role + 1;
      const int E = (role < NJ) ? (SEGLEN * (role + 1)) : (TT - 1);
      float P = base[(size_t)s0 * UU + cstoS];
      // --- first WSAVE rows: step + stash logit column to g_slog ---
      {
        float* sp = &g_slog[(((size_t)b * NJ + (role - 1)) * WSAVE) * 64 + lane];
        const int A = s0 + 1;
#pragma unroll
        for (int i = 0; i < 16; ++i) bufA[i] = base[(size_t)(A + i) * UU + tgtS];
#pragma unroll 1
        for (int ch = 0; ch < 3; ++ch) {        // 3 chunks x 32 = 96 rows
          const int t0c = A + ch * 32;
#pragma unroll
          for (int i = 0; i < 16; ++i) bufB[i] = base[(size_t)(t0c + 16 + i) * UU + tgtS];
#pragma unroll
          for (int i = 0; i < 16; ++i) { sp[(size_t)(ch * 32 + i) * 64] = bufA[i]; K2_FSTEP(t0c + i, bufA[i]); }
#pragma unroll
          for (int i = 0; i < 16; ++i) bufA[i] = base[(size_t)(t0c + 32 + i) * UU + tgtS];
#pragma unroll
          for (int i = 0; i < 16; ++i) { sp[(size_t)(ch * 32 + 16 + i) * 64] = bufB[i]; K2_FSTEP(t0c + 16 + i, bufB[i]); }
        }
      }
      K2_RUNSEG(s0 + 1 + WSAVE, E);
      g_bound[((b << 4) + role) * 64 + lane] = P;
    }
    return;
  }
#endif

  // ---------------- fallback: R2 bpermute alternating S/D scheme, FULL chain
  if (role != 0) return;
  {
    float tvD[16];
#pragma unroll
    for (int s = 0; s < 16; ++s) {
      const int rp = dirp ? ((q + s) & 15) : ((q - s) & 15);
      tvD[s] = trans[(bit4 * 16 + rp) * UU + cstoS];
    }
    const int idx32 = (lane ^ 32) << 2;
    const int idx48 = (lane ^ 48) << 2;
    float P = base[cstoS];

#define K2_BSTEP(tval, lg, TVHI, XIDX, SCOL) do {                            \
    const float g0 = P + (TVHI)[0];                                          \
    const float g1 = ROTF(1) + (TVHI)[1];                                    \
    const float g2 = ROTF(2) + (TVHI)[2];                                    \
    const float g3 = ROTF(3) + (TVHI)[3];                                    \
    const float g4 = ROTF(4) + (TVHI)[4];                                    \
    const float g5 = ROTF(5) + (TVHI)[5];                                    \
    const float g6 = ROTF(6) + (TVHI)[6];                                    \
    const float g7 = ROTF(7) + (TVHI)[7];                                    \
    const float g8 = ROTF(8) + (TVHI)[8];                                    \
    const float g9 = ROTF(9) + (TVHI)[9];                                    \
    const float g10 = ROTF(10) + (TVHI)[10];                                 \
    const float g11 = ROTF(11) + (TVHI)[11];                                 \
    const float g12 = ROTF(12) + (TVHI)[12];                                 \
    const float g13 = ROTF(13) + (TVHI)[13];                                 \
    const float g14 = ROTF(14) + (TVHI)[14];                                 \
    const float g15 = ROTF(15) + (TVHI)[15];                                 \
    const float h0 = fmaxf(fmaxf(g0, g1), g2);                               \
    const float h1 = fmaxf(fmaxf(g3, g4), g5);                               \
    const float h2 = fmaxf(fmaxf(g6, g7), g8);                               \
    const float h3 = fmaxf(fmaxf(g9, g10), g11);                             \
    const float h4 = fmaxf(fmaxf(g12, g13), g14);                            \
    const float k0 = fmaxf(fmaxf(h0, h1), h2);                               \
    const float k1 = fmaxf(fmaxf(h3, h4), g15);                              \
    const float pm2 = fmaxf(k0, k1);                                         \
    const int po = __builtin_amdgcn_ds_bpermute((XIDX), __float_as_int(pm2));\
    P = fmaxf(pm2, __int_as_float(po)) + (lg);                               \
    base[(size_t)(tval) * UU + (SCOL)] = P;                                  \
  } while (0)

#pragma unroll
    for (int i = 0; i < 16; ++i)
      bufA[i] = base[(size_t)(1 + i) * UU + ((i & 1) ? cstoS : tgtS)];
#pragma unroll 1
    for (int tc = 1; tc <= 1985; tc += 32) {
#pragma unroll
      for (int i = 0; i < 16; ++i)
        bufB[i] = base[(size_t)(tc + 16 + i) * UU + ((i & 1) ? cstoS : tgtS)];
#pragma unroll
      for (int i = 0; i < 16; ++i) {
        if ((i & 1) == 0) K2_BSTEP(tc + i, bufA[i], tvS, idx32, tgtS);
        else              K2_BSTEP(tc + i, bufA[i], tvD, idx48, cstoS);
      }
#pragma unroll
      for (int i = 0; i < 16; ++i)
        bufA[i] = base[(size_t)(tc + 32 + i) * UU + ((i & 1) ? cstoS : tgtS)];
#pragma unroll
      for (int i = 0; i < 16; ++i) {
        if ((i & 1) == 0) K2_BSTEP(tc + 16 + i, bufB[i], tvS, idx32, tgtS);
        else              K2_BSTEP(tc + 16 + i, bufB[i], tvD, idx48, cstoS);
      }
    }
#pragma unroll
    for (int i = 0; i < 16; ++i) {
      int r = 2033 + i; if (r > TT - 1) r = TT - 1;
      bufB[i] = base[(size_t)r * UU + ((i & 1) ? cstoS : tgtS)];
    }
#pragma unroll
    for (int i = 0; i < 16; ++i) {
      if ((i & 1) == 0) K2_BSTEP(2017 + i, bufA[i], tvS, idx32, tgtS);
      else              K2_BSTEP(2017 + i, bufA[i], tvD, idx48, cstoS);
    }
#pragma unroll
    for (int i = 0; i < 15; ++i) {
      if ((i & 1) == 0) K2_BSTEP(2033 + i, bufB[i], tvS, idx32, tgtS);
      else              K2_BSTEP(2033 + i, bufB[i], tvD, idx48, cstoS);
    }
  }
}

// ---------------------------------------------------------------------------
// K2b: PARALLEL junction scans — NJ*64 blocks, all independent.
// FAST path (rows jr+1..jr+WSAVE): true chain stepped with the ONE verified
// K2_FSTEP using stashed logits; coupling detected via d = P - specRow
// (== Mt - Ms identically). SLOW tail (> WSAVE rows, <=31): the R14-verified
// two-tree transport loop, byte-identical.
// ---------------------------------------------------------------------------
__global__ __launch_bounds__(64) void k2b_fixup(float* __restrict__ lb,
                                                const float* __restrict__ trans) {
  const int lane = threadIdx.x;
  const int b = blockIdx.x & 63;
  const int j = (blockIdx.x >> 6) + 1;            // 1..NJ
  const int q = lane & 15;
  const int bit4 = (lane >> 4) & 1;
  const int bit5v = (lane >> 5) & 1;
  const int hiS = bit4 ^ bit5v;
  const int tgtS = bit4 * 16 + q;
  const int cstoS = hiS * 16 + q;
  const int jr = SEGLEN * j + 1;
  const int segEnd = (j < NJ) ? (SEGLEN * (j + 1)) : (TT - 1);

  const int probe = __builtin_amdgcn_update_dpp(0, q, 0x121, 0xF, 0xF, false);
  const bool dirp = (probe == ((q + 1) & 15));

  float tvS[16];
#pragma unroll
  for (int s = 0; s < 16; ++s) {
    const int rp = dirp ? ((q + s) & 15) : ((q - s) & 15);
    tvS[s] = trans[(hiS * 16 + rp) * UU + tgtS];
  }

#ifdef K2_HAVE_PERMLANE
  v2u p32 = __builtin_amdgcn_permlane32_swap((unsigned)lane, (unsigned)lane, false, false);
  v2u p16 = __builtin_amdgcn_permlane16_swap((unsigned)lane, (unsigned)lane, false, false);
  const bool c32ok = ((int)p32.x == (lane ^ 32)) || ((int)p32.y == (lane ^ 32));
  const bool c16ok = ((int)p16.x == (lane ^ 16)) || ((int)p16.y == (lane ^ 16));
  const bool m16sel = ((int)p16.x == (lane ^ 16));
  const bool okSwap = (__ballot(c32ok) == ~0ull) && (__ballot(c16ok) == ~0ull);
  if (!okSwap) {
    if (lane == 0) { g_ts[b * NJ + j - 1] = segEnd; g_c[b * NJ + j - 1] = 0.0f; }
    return;  // fallback path computed the full true chain already
  }

  float* base = lb + (size_t)b * TT * UU;
  const float TAU = 0.05f;

  float P = g_bound[((b << 4) + (j - 1)) * 64 + lane];      // prev boundary
  const float lgj = base[(size_t)jr * UU + tgtS];           // junction logits
  K2_FSTEP(jr, lgj);                                        // row jr <- true-rel-ref

  const float* sp = &g_slog[(((size_t)b * NJ + (j - 1)) * WSAVE) * 64 + lane];

  float ring[4];
#pragma unroll
  for (int i = 0; i < 4; ++i) ring[i] = base[(size_t)(jr + 1 + i) * UU + cstoS];

  int ts_rec = segEnd; float c_rec = 0.0f; bool done = false;
  float lastSpec = 0.0f;

  // ---- fast scan: rows jr+1 .. jr+WSAVE (one tree per step) ----
#pragma unroll 1
  for (int w = 0; w < WSAVE; ++w) {
    const int t = jr + 1 + w;
    const float specRow = ring[w & 3];
    const int pf = t + 4;
    if (pf <= segEnd) ring[w & 3] = base[(size_t)pf * UU + cstoS];
    const float lg = sp[(size_t)w * 64];
    K2_FSTEP(t, lg);                        // P = true-rel-ref alpha, stored
    const float d = P - specRow;            // == Mt - Ms identically
    const float dref = __uint_as_float(
        (unsigned)__builtin_amdgcn_readfirstlane(__float_as_int(d)));
    const bool uni = (__ballot(fabsf(d - dref) <= TAU) == ~0ull);
    lastSpec = specRow;
    if (uni) { ts_rec = t; c_rec = dref; done = true; break; }
  }

  // ---- slow tail: rows jr+WSAVE+1 .. segEnd (two-tree transport) ----
  if (!done) {
    float trueP = P;
    float specP = lastSpec;                 // spec row at t = jr+WSAVE
#pragma unroll
    for (int i = 0; i < 4; ++i) {
      int r = jr + WSAVE + 1 + i; if (r > segEnd) r = segEnd;
      ring[i] = base[(size_t)r * UU + cstoS];
    }
#pragma unroll 1
    for (int t = jr + WSAVE + 1; t <= segEnd; ++t) {
      const float specRow = ring[(t - (jr + WSAVE + 1)) & 3];
      const int pf = t + 4;
      if (pf <= segEnd) ring[(t - (jr + WSAVE + 1)) & 3] = base[(size_t)pf * UU + cstoS];
      const float Mt = k2_mcomb(trueP, tvS);
      const float Ms = k2_mcomb(specP, tvS);
      const float d = Mt - Ms;
      v2u s16d = __builtin_amdgcn_permlane16_swap(__float_as_uint(d),
                                                  __float_as_uint(d), false, false);
      const float dx = m16sel ? __uint_as_float(s16d.x) : __uint_as_float(s16d.y);
      const float dsel = bit5v ? dx : d;
      const float nt = specRow + dsel;
      base[(size_t)t * UU + cstoS] = nt;
      const float dref = __uint_as_float(
          (unsigned)__builtin_amdgcn_readfirstlane(__float_as_int(d)));
      const bool uni = (__ballot(fabsf(d - dref) <= TAU) == ~0ull);
      trueP = nt;
      specP = specRow;
      if (uni) { ts_rec = t; c_rec = dref; break; }
    }
  }
  if (lane == 0) { g_ts[b * NJ + j - 1] = ts_rec; g_c[b * NJ + j - 1] = c_rec; }
#else
  if (lane == 0) { g_ts[b * NJ + j - 1] = segEnd; g_c[b * NJ + j - 1] = 0.0f; }
#endif
}

// ---------------------------------------------------------------------------
// K3: backpointers; applies alpha offsets during the LDS load (row-uniform
// adds don't change the per-(t,u) argmax). off(row): jj=(row-1)>>SEGSH;
// jj==0 -> 0; else rows [jr,ts_jj] -> C[jj-1], (ts_jj, E_jj] -> C[jj].
// ---------------------------------------------------------------------------
__global__ __launch_bounds__(256) void k3_bp(const float* __restrict__ lb,
                                             const float* __restrict__ trans,
                                             const int* __restrict__ nwords,
                                             unsigned char* __restrict__ bp) {
  __shared__ float as[129 * 32];
  __shared__ float ts[32 * 32];
  const int b = blockIdx.x >> 4;
  const int c = blockIdx.x & 15;
  const int t0 = 128 * c;
  const int tid = threadIdx.x;
  const float* base = lb + (size_t)b * TT * UU;
  const int nw = nwords[b];

  float C[NSEG];
  int TS[NSEG];
  C[0] = 0.0f; TS[0] = 0;
#pragma unroll
  for (int j = 1; j <= NJ; ++j) {
    C[j] = C[j - 1] + g_c[b * NJ + j - 1];
    TS[j] = g_ts[b * NJ + j - 1];
  }

  for (int idx = tid; idx < 129 * 32; idx += 256) {
    const int gidx = (t0 - 1) * 32 + idx;
    float v = 0.0f;
    if (gidx >= 0 && gidx < TT * UU) {
      const int row = (t0 - 1) + (idx >> 5);
      const int jj = (row - 1) >> SEGSH;      // 0 for rows 0..SEGLEN
      float off = 0.0f;
      if (jj >= 1) off = (row <= TS[jj]) ? C[jj - 1] : C[jj];
      v = base[gidx] + off;
    }
    as[idx] = v;
  }
  for (int idx = tid; idx < 1024; idx += 256) ts[idx] = trans[idx];
  __syncthreads();

  const int u = tid & 31;
  const int tg = tid >> 5;
  unsigned char* bpu = bp + ((size_t)b * 32 + u) * TT;

#pragma unroll 1
  for (int qq = 0; qq < 4; ++qq) {
    const int tl0 = tg * 16 + qq * 4;
    unsigned int pack = 0;
#pragma unroll
    for (int e = 0; e < 4; ++e) {
      const int tl = tl0 + e;
      const int t = t0 + tl;
      int idx;
      if (t >= 1 && t < nw) {
        float m = as[tl * 32 + 0] + ts[0 * 32 + u];
        idx = 0;
#pragma unroll
        for (int v = 1; v < 32; ++v) {
          const float cv = as[tl * 32 + v] + ts[v * 32 + u];
          if (cv > m) { m = cv; idx = v; }
        }
      } else {
        idx = u;
      }
      pack |= ((unsigned int)idx) << (8 * e);
    }
    *(unsigned int*)(bpu + t0 + tl0) = pack;
  }
}

// ---------------------------------------------------------------------------
// K4: backtrace + best_score; applies off(nw-1) to its single alpha row read.
// ---------------------------------------------------------------------------
__global__ __launch_bounds__(64) void k4_backtrace(const float* __restrict__ lb,
                                                   const unsigned char* __restrict__ bp,
                                                   const int* __restrict__ nwords,
                                                   int* __restrict__ pred,
                                                   float* __restrict__ score) {
  const int b = blockIdx.x;
  const int lane = threadIdx.x;
  const int u = lane & 31;
  const int h = lane >> 5;
  const int nw = nwords[b];

  float off = 0.0f;
  {
    const int row = nw - 1;
    const int jj = (row - 1) >> SEGSH;
    if (jj >= 1) {
      float Cacc = 0.0f;
      float Cprev = 0.0f;
#pragma unroll
      for (int j = 1; j <= NJ; ++j) {
        Cprev = Cacc;
        Cacc += g_c[b * NJ + j - 1];
        if (j == jj) off = (row <= g_ts[b * NJ + j - 1]) ? Cprev : Cacc;
      }
    }
  }

  const float a = lb[((size_t)b * TT + (nw - 1)) * UU + u] + off;
  float m = a;
#pragma unroll
  for (int s = 32; s; s >>= 1) m = fmaxf(m, __shfl_xor(m, s));
  if (lane == 0) score[b] = m;
  const unsigned long long mask = __ballot(lane < 32 && a == m);
  int tag = __ffsll((unsigned long long)mask) - 1;
  tag = __builtin_amdgcn_readfirstlane(tag);

  int* predb = pred + b * TT;
  for (int p = nw - 1 + lane; p < TT; p += 64) predb[p] = tag;
  if (nw < 2) return;

  const unsigned char* bpb = bp + (size_t)b * 32 * TT;
  const int pcmax = (nw - 2) >> 6;
  const int thi_top = nw - 1;

  int wprev0 = 0;
  {
    const int toff = (pcmax + 1) * 64;
    if (toff < TT) wprev0 = *(const int*)(bpb + (size_t)u * TT + toff);
  }

  for (int pc = pcmax; pc >= 0; --pc) {
    int wreg[8];
#pragma unroll
    for (int j = 0; j < 8; ++j)
      wreg[j] = *(const int*)(bpb + (size_t)u * TT + pc * 64 + 4 * (h * 8 + j));
    int predv = 0;

    if (pc == pcmax) {
      const int thi = thi_top;
      if (pc * 64 + 64 <= thi) {
        const int val = __builtin_amdgcn_readlane(wprev0, tag);
        tag = __builtin_amdgcn_readfirstlane(val & 0xFF);
        if (lane == 63) predv = tag;
      }
#pragma unroll
      for (int lt = 63; lt >= 1; --lt) {
        if (pc * 64 + lt <= thi) {
          const int d = lt >> 2, byte = lt & 3;
          const int hs = d >> 3, j = d & 7;
          const int val = __builtin_amdgcn_readlane(wreg[j], hs * 32 + tag);
          tag = __builtin_amdgcn_readfirstlane((val >> (8 * byte)) & 0xFF);
          if (lane == lt - 1) predv = tag;
        }
      }
      const int lim = thi - pc * 64;
      if (lane < lim) predb[pc * 64 + lane] = predv;
    } else {
      {
        const int val = __builtin_amdgcn_readlane(wprev0, tag);
        tag = __builtin_amdgcn_readfirstlane(val & 0xFF);
        if (lane == 63) predv = tag;
      }
#pragma unroll
      for (int lt = 63; lt >= 1; --lt) {
        const int d = lt >> 2, byte = lt & 3;
        const int hs = d >> 3, j = d & 7;
        const int val = __builtin_amdgcn_readlane(wreg[j], hs * 32 + tag);
        tag = __builtin_amdgcn_readfirstlane((val >> (8 * byte)) & 0xFF);
        if (lane == lt - 1) predv = tag;
      }
      predb[pc * 64 + lane] = predv;
    }
    wprev0 = wreg[0];
  }
}

// ---------------------------------------------------------------------------
extern "C" void kernel_launch(void* const* d_in, const int* in_sizes, int n_in,
                              void* d_out, int out_size, void* d_ws, size_t ws_size,
                              hipStream_t stream) {
  const float* x = (const float*)d_in[0];
  const int* nwords = (const int*)d_in[1];
  const float* kern = (const float*)d_in[2];
  const float* chain = (const float*)d_in[3];
  const float* bias = (const float*)d_in[4];

  float* logits = (float*)d_ws;                                        // 16 MB
  unsigned char* bp = (unsigned char*)d_ws + (size_t)BB * TT * UU * 4; // +4 MB

  int* pred = (int*)d_out;
  float* score = (float*)d_out + (size_t)BB * TT;

  k1_logits<<<dim3(512), dim3(256), 0, stream>>>(x, kern, bias, logits);
  k2a_forward<<<dim3(NSEG * 64), dim3(64), 0, stream>>>(logits, chain);
  k2b_fixup<<<dim3(NJ * 64), dim3(64), 0, stream>>>(logits, chain);
  k3_bp<<<dim3(BB * 16), dim3(256), 0, stream>>>(logits, chain, nwords, bp);
  k4_backtrace<<<dim3(BB), dim3(64), 0, stream>>>(logits, bp, nwords, pred, score);
}

// Round 19
// 172.497 us; speedup vs baseline: 1.0322x; 1.0322x over previous
//
#include <hip/hip_runtime.h>

#define BB 64
#define TT 2048
#define DD 512
#define UU 32

// Speculation geometry: NSEG segments of SEGLEN rows; junction j (1..NJ) at
// row SEGLEN*j+1. Chained-parallel scans (R14/R16-verified algebra):
//   C[0]=0, C[j]=C[j-1]+c'_j; rows [jr_j, ts_j] hold true-C[j-1], rows
//   (ts_j, E_j] hold spec = true-C[j]. Offsets applied at read time in k3/k4.
#define NSEG 16
#define SEGLEN 128            // TT/NSEG
#define SEGSH 7               // log2(SEGLEN)
#define NJ (NSEG - 1)

__device__ int g_ts[BB * NJ];
__device__ float g_c[BB * NJ];
__device__ float g_bound[BB * NSEG * 64];

// ---------------------------------------------------------------------------
// K1: logits GEMM (R15-verified: 256-row geometry + k-pair x-reads).
// ---------------------------------------------------------------------------
__global__ __launch_bounds__(256) void k1_logits(const float* __restrict__ x,
                                                 const float* __restrict__ w,
                                                 const float* __restrict__ bias,
                                                 float* __restrict__ out) {
  __shared__ float xs[256 * 34];
  __shared__ float wsh[32 * 36];
  const int tid = threadIdx.x;
  const long row0 = (long)blockIdx.x * 256;
  const int tr = tid >> 2;
  const int tc = tid & 3;
  const int ubase = tc * 8;
  const int sr = tid >> 3;
  const int sc = (tid & 7) * 4;

  float acc[4][8];
#pragma unroll
  for (int i = 0; i < 4; ++i)
#pragma unroll
    for (int j = 0; j < 8; ++j) acc[i][j] = 0.0f;

  for (int kc = 0; kc < DD; kc += 32) {
#pragma unroll
    for (int p = 0; p < 8; ++p) {
      const int r = p * 32 + sr;
      const float4 v = *(const float4*)(x + (row0 + r) * DD + kc + sc);
      *(float2*)(&xs[r * 34 + sc]) = make_float2(v.x, v.y);
      *(float2*)(&xs[r * 34 + sc + 2]) = make_float2(v.z, v.w);
    }
    {
      const int k = tid >> 3;
      const int uu4 = (tid & 7) * 4;
      const float4 v = *(const float4*)(w + (size_t)(kc + k) * UU + uu4);
      *(float4*)(&wsh[k * 36 + uu4]) = v;
    }
    __syncthreads();
#pragma unroll
    for (int kp = 0; kp < 16; ++kp) {
      const int k = kp * 2;
      const float4 wa0 = *(const float4*)(&wsh[k * 36 + ubase]);
      const float4 wa1 = *(const float4*)(&wsh[k * 36 + ubase + 4]);
      const float4 wb0 = *(const float4*)(&wsh[(k + 1) * 36 + ubase]);
      const float4 wb1 = *(const float4*)(&wsh[(k + 1) * 36 + ubase + 4]);
      const float wva[8] = {wa0.x, wa0.y, wa0.z, wa0.w, wa1.x, wa1.y, wa1.z, wa1.w};
      const float wvb[8] = {wb0.x, wb0.y, wb0.z, wb0.w, wb1.x, wb1.y, wb1.z, wb1.w};
#pragma unroll
      for (int i = 0; i < 4; ++i) {
        const float2 xv2 = *(const float2*)(&xs[(tr + 64 * i) * 34 + k]);
#pragma unroll
        for (int j = 0; j < 8; ++j) acc[i][j] = fmaf(xv2.x, wva[j], acc[i][j]);
#pragma unroll
        for (int j = 0; j < 8; ++j) acc[i][j] = fmaf(xv2.y, wvb[j], acc[i][j]);
      }
    }
    __syncthreads();
  }
  float bv[8];
#pragma unroll
  for (int j = 0; j < 8; ++j) bv[j] = bias[ubase + j];
#pragma unroll
  for (int i = 0; i < 4; ++i) {
    const long row = row0 + tr + 64 * i;
    float4 o0, o1;
    o0.x = acc[i][0] + bv[0]; o0.y = acc[i][1] + bv[1];
    o0.z = acc[i][2] + bv[2]; o0.w = acc[i][3] + bv[3];
    o1.x = acc[i][4] + bv[4]; o1.y = acc[i][5] + bv[5];
    o1.z = acc[i][6] + bv[6]; o1.w = acc[i][7] + bv[7];
    *(float4*)(out + row * UU + ubase) = o0;
    *(float4*)(out + row * UU + ubase + 4) = o1;
  }
}

// ======================= K2 common machinery (R7-verified) ==================

#define ROTF(S) \
  __int_as_float(__builtin_amdgcn_update_dpp(0, __float_as_int(P), 0x120 + (S), 0xF, 0xF, true))

#define K2_TREE                                                              \
    const float c0 = P + tvS[0];                                             \
    const float c1 = ROTF(1) + tvS[1];                                       \
    const float c2 = ROTF(2) + tvS[2];                                       \
    const float c3 = ROTF(3) + tvS[3];                                       \
    const float c4 = ROTF(4) + tvS[4];                                       \
    const float c5 = ROTF(5) + tvS[5];                                       \
    const float c6 = ROTF(6) + tvS[6];                                       \
    const float c7 = ROTF(7) + tvS[7];                                       \
    const float c8 = ROTF(8) + tvS[8];                                       \
    const float c9 = ROTF(9) + tvS[9];                                       \
    const float c10 = ROTF(10) + tvS[10];                                    \
    const float c11 = ROTF(11) + tvS[11];                                    \
    const float c12 = ROTF(12) + tvS[12];                                    \
    const float c13 = ROTF(13) + tvS[13];                                    \
    const float c14 = ROTF(14) + tvS[14];                                    \
    const float c15 = ROTF(15) + tvS[15];                                    \
    const float d0 = fmaxf(fmaxf(c0, c1), c2);                               \
    const float d1 = fmaxf(fmaxf(c3, c4), c5);                               \
    const float d2 = fmaxf(fmaxf(c6, c7), c8);                               \
    const float d3 = fmaxf(fmaxf(c9, c10), c11);                             \
    const float d4 = fmaxf(fmaxf(c12, c13), c14);                            \
    const float e0 = fmaxf(fmaxf(d0, d1), d2);                               \
    const float e1 = fmaxf(fmaxf(d3, d4), c15);                              \
    const float pm = fmaxf(e0, e1);

#if __has_builtin(__builtin_amdgcn_permlane32_swap) && __has_builtin(__builtin_amdgcn_permlane16_swap)
#define K2_HAVE_PERMLANE 1
typedef unsigned int v2u __attribute__((ext_vector_type(2)));

#define K2_FSTEP(tval, lg) do {                                              \
    K2_TREE                                                                  \
    v2u s32 = __builtin_amdgcn_permlane32_swap(__float_as_uint(pm),          \
                                               __float_as_uint(pm), false, false); \
    const float pd = fmaxf(__uint_as_float(s32.x), __uint_as_float(s32.y)) + (lg); \
    v2u s16 = __builtin_amdgcn_permlane16_swap(__float_as_uint(pd),          \
                                               __float_as_uint(pd), false, false); \
    const float cx = m16sel ? __uint_as_float(s16.x) : __uint_as_float(s16.y); \
    P = bit5v ? cx : pd;                                                     \
    base[(size_t)(tval) * UU + cstoS] = P;                                   \
  } while (0)

// combined pre-logit max (bitwise-identical tree + swap32 fold of K2_FSTEP)
__device__ __forceinline__ float k2_mcomb(float P, const float* tvS) {
  K2_TREE
  v2u s32 = __builtin_amdgcn_permlane32_swap(__float_as_uint(pm),
                                             __float_as_uint(pm), false, false);
  return fmaxf(__uint_as_float(s32.x), __uint_as_float(s32.y));
}

// generic segment runner: steps rows [A_,E_] with live P (clamped prefetch,
// no reads beyond E_ -> no cross-role races in k2a).
#define K2_RUNSEG(A_, E_) do {                                               \
    int tcc = (A_);                                                          \
    _Pragma("unroll")                                                        \
    for (int i = 0; i < 16; ++i) {                                           \
      int r = (A_) + i; if (r > (E_)) r = (E_);                              \
      bufA[i] = base[(size_t)r * UU + tgtS];                                 \
    }                                                                        \
    _Pragma("unroll 1")                                                      \
    for (; tcc + 31 <= (E_); tcc += 32) {                                    \
      _Pragma("unroll")                                                      \
      for (int i = 0; i < 16; ++i) bufB[i] = base[(size_t)(tcc + 16 + i) * UU + tgtS]; \
      _Pragma("unroll")                                                      \
      for (int i = 0; i < 16; ++i) K2_FSTEP(tcc + i, bufA[i]);               \
      _Pragma("unroll")                                                      \
      for (int i = 0; i < 16; ++i) {                                         \
        int r = tcc + 32 + i; if (r > (E_)) r = (E_);                        \
        bufA[i] = base[(size_t)r * UU + tgtS];                               \
      }                                                                      \
      _Pragma("unroll")                                                      \
      for (int i = 0; i < 16; ++i) K2_FSTEP(tcc + 16 + i, bufB[i]);          \
    }                                                                        \
    const int rem = (E_) - tcc + 1;                                          \
    if (rem > 0) {                                                           \
      _Pragma("unroll")                                                      \
      for (int i = 0; i < 16; ++i) {                                         \
        int r = tcc + 16 + i; if (r > (E_)) r = (E_);                        \
        bufB[i] = base[(size_t)r * UU + tgtS];                               \
      }                                                                      \
      _Pragma("unroll")                                                      \
      for (int i = 0; i < 16; ++i) { if (i < rem) K2_FSTEP(tcc + i, bufA[i]); } \
      _Pragma("unroll")                                                      \
      for (int i = 0; i < 16; ++i) { if (16 + i < rem) K2_FSTEP(tcc + 16 + i, bufB[i]); } \
    }                                                                        \
  } while (0)
#endif

// ---------------------------------------------------------------------------
// K2a: S=NSEG speculation. NSEG*64 blocks.
//  role 0: TRUE rows 1..SEGLEN; saves boundary vector to g_bound slot 0.
//  role j: SPECULATIVE from fresh start at logits[SEGLEN*j+1] (junction row
//  untouched), rows SEGLEN*j+2..E_j; saves boundary vector to slot j.
// ---------------------------------------------------------------------------
__global__ __launch_bounds__(64) void k2a_forward(float* __restrict__ lb,
                                                  const float* __restrict__ trans) {
  const int lane = threadIdx.x;
  const int q = lane & 15;
  const int bit4 = (lane >> 4) & 1;
  const int bit5v = (lane >> 5) & 1;
  const int hiS = bit4 ^ bit5v;
  const int tgtS = bit4 * 16 + q;
  const int cstoS = hiS * 16 + q;
  const int role = blockIdx.x >> 6;
  const int b = blockIdx.x & 63;

  const int probe = __builtin_amdgcn_update_dpp(0, q, 0x121, 0xF, 0xF, false);
  const bool dirp = (probe == ((q + 1) & 15));

  float tvS[16];
#pragma unroll
  for (int s = 0; s < 16; ++s) {
    const int rp = dirp ? ((q + s) & 15) : ((q - s) & 15);
    tvS[s] = trans[(hiS * 16 + rp) * UU + tgtS];
  }

  float* base = lb + (size_t)b * TT * UU;
  float bufA[16], bufB[16];

#ifdef K2_HAVE_PERMLANE
  v2u p32 = __builtin_amdgcn_permlane32_swap((unsigned)lane, (unsigned)lane, false, false);
  v2u p16 = __builtin_amdgcn_permlane16_swap((unsigned)lane, (unsigned)lane, false, false);
  const bool c32ok = ((int)p32.x == (lane ^ 32)) || ((int)p32.y == (lane ^ 32));
  const bool c16ok = ((int)p16.x == (lane ^ 16)) || ((int)p16.y == (lane ^ 16));
  const bool m16sel = ((int)p16.x == (lane ^ 16));
  const bool okSwap = (__ballot(c32ok) == ~0ull) && (__ballot(c16ok) == ~0ull);

  if (okSwap) {
    if (role == 0) {
      float P = base[cstoS];
      K2_RUNSEG(1, SEGLEN);
      g_bound[((b << 4) + 0) * 64 + lane] = P;
    } else {
      const int s0 = SEGLEN * role + 1;
      const int E = (role < NJ) ? (SEGLEN * (role + 1)) : (TT - 1);
      float P = base[(size_t)s0 * UU + cstoS];
      K2_RUNSEG(s0 + 1, E);
      g_bound[((b << 4) + role) * 64 + lane] = P;
    }
    return;
  }
#endif

  // ---------------- fallback: R2 bpermute alternating S/D scheme, FULL chain
  if (role != 0) return;
  {
    float tvD[16];
#pragma unroll
    for (int s = 0; s < 16; ++s) {
      const int rp = dirp ? ((q + s) & 15) : ((q - s) & 15);
      tvD[s] = trans[(bit4 * 16 + rp) * UU + cstoS];
    }
    const int idx32 = (lane ^ 32) << 2;
    const int idx48 = (lane ^ 48) << 2;
    float P = base[cstoS];

#define K2_BSTEP(tval, lg, TVHI, XIDX, SCOL) do {                            \
    const float g0 = P + (TVHI)[0];                                          \
    const float g1 = ROTF(1) + (TVHI)[1];                                    \
    const float g2 = ROTF(2) + (TVHI)[2];                                    \
    const float g3 = ROTF(3) + (TVHI)[3];                                    \
    const float g4 = ROTF(4) + (TVHI)[4];                                    \
    const float g5 = ROTF(5) + (TVHI)[5];                                    \
    const float g6 = ROTF(6) + (TVHI)[6];                                    \
    const float g7 = ROTF(7) + (TVHI)[7];                                    \
    const float g8 = ROTF(8) + (TVHI)[8];                                    \
    const float g9 = ROTF(9) + (TVHI)[9];                                    \
    const float g10 = ROTF(10) + (TVHI)[10];                                 \
    const float g11 = ROTF(11) + (TVHI)[11];                                 \
    const float g12 = ROTF(12) + (TVHI)[12];                                 \
    const float g13 = ROTF(13) + (TVHI)[13];                                 \
    const float g14 = ROTF(14) + (TVHI)[14];                                 \
    const float g15 = ROTF(15) + (TVHI)[15];                                 \
    const float h0 = fmaxf(fmaxf(g0, g1), g2);                               \
    const float h1 = fmaxf(fmaxf(g3, g4), g5);                               \
    const float h2 = fmaxf(fmaxf(g6, g7), g8);                               \
    const float h3 = fmaxf(fmaxf(g9, g10), g11);                             \
    const float h4 = fmaxf(fmaxf(g12, g13), g14);                            \
    const float k0 = fmaxf(fmaxf(h0, h1), h2);                               \
    const float k1 = fmaxf(fmaxf(h3, h4), g15);                              \
    const float pm2 = fmaxf(k0, k1);                                         \
    const int po = __builtin_amdgcn_ds_bpermute((XIDX), __float_as_int(pm2));\
    P = fmaxf(pm2, __int_as_float(po)) + (lg);                               \
    base[(size_t)(tval) * UU + (SCOL)] = P;                                  \
  } while (0)

#pragma unroll
    for (int i = 0; i < 16; ++i)
      bufA[i] = base[(size_t)(1 + i) * UU + ((i & 1) ? cstoS : tgtS)];
#pragma unroll 1
    for (int tc = 1; tc <= 1985; tc += 32) {
#pragma unroll
      for (int i = 0; i < 16; ++i)
        bufB[i] = base[(size_t)(tc + 16 + i) * UU + ((i & 1) ? cstoS : tgtS)];
#pragma unroll
      for (int i = 0; i < 16; ++i) {
        if ((i & 1) == 0) K2_BSTEP(tc + i, bufA[i], tvS, idx32, tgtS);
        else              K2_BSTEP(tc + i, bufA[i], tvD, idx48, cstoS);
      }
#pragma unroll
      for (int i = 0; i < 16; ++i)
        bufA[i] = base[(size_t)(tc + 32 + i) * UU + ((i & 1) ? cstoS : tgtS)];
#pragma unroll
      for (int i = 0; i < 16; ++i) {
        if ((i & 1) == 0) K2_BSTEP(tc + 16 + i, bufB[i], tvS, idx32, tgtS);
        else              K2_BSTEP(tc + 16 + i, bufB[i], tvD, idx48, cstoS);
      }
    }
#pragma unroll
    for (int i = 0; i < 16; ++i) {
      int r = 2033 + i; if (r > TT - 1) r = TT - 1;
      bufB[i] = base[(size_t)r * UU + ((i & 1) ? cstoS : tgtS)];
    }
#pragma unroll
    for (int i = 0; i < 16; ++i) {
      if ((i & 1) == 0) K2_BSTEP(2017 + i, bufA[i], tvS, idx32, tgtS);
      else              K2_BSTEP(2017 + i, bufA[i], tvD, idx48, cstoS);
    }
#pragma unroll
    for (int i = 0; i < 15; ++i) {
      if ((i & 1) == 0) K2_BSTEP(2033 + i, bufB[i], tvS, idx32, tgtS);
      else              K2_BSTEP(2033 + i, bufB[i], tvD, idx48, cstoS);
    }
  }
}

// ---------------------------------------------------------------------------
// K2b: PARALLEL junction scans — NJ*64 blocks, all independent.
// (R14-verified scan loop, byte-identical; geometry parameterized.)
// ---------------------------------------------------------------------------
__global__ __launch_bounds__(64) void k2b_fixup(float* __restrict__ lb,
                                                const float* __restrict__ trans) {
  const int lane = threadIdx.x;
  const int b = blockIdx.x & 63;
  const int j = (blockIdx.x >> 6) + 1;            // 1..NJ
  const int q = lane & 15;
  const int bit4 = (lane >> 4) & 1;
  const int bit5v = (lane >> 5) & 1;
  const int hiS = bit4 ^ bit5v;
  const int tgtS = bit4 * 16 + q;
  const int cstoS = hiS * 16 + q;
  const int jr = SEGLEN * j + 1;
  const int segEnd = (j < NJ) ? (SEGLEN * (j + 1)) : (TT - 1);

  const int probe = __builtin_amdgcn_update_dpp(0, q, 0x121, 0xF, 0xF, false);
  const bool dirp = (probe == ((q + 1) & 15));

  float tvS[16];
#pragma unroll
  for (int s = 0; s < 16; ++s) {
    const int rp = dirp ? ((q + s) & 15) : ((q - s) & 15);
    tvS[s] = trans[(hiS * 16 + rp) * UU + tgtS];
  }

#ifdef K2_HAVE_PERMLANE
  v2u p32 = __builtin_amdgcn_permlane32_swap((unsigned)lane, (unsigned)lane, false, false);
  v2u p16 = __builtin_amdgcn_permlane16_swap((unsigned)lane, (unsigned)lane, false, false);
  const bool c32ok = ((int)p32.x == (lane ^ 32)) || ((int)p32.y == (lane ^ 32));
  const bool c16ok = ((int)p16.x == (lane ^ 16)) || ((int)p16.y == (lane ^ 16));
  const bool m16sel = ((int)p16.x == (lane ^ 16));
  const bool okSwap = (__ballot(c32ok) == ~0ull) && (__ballot(c16ok) == ~0ull);
  if (!okSwap) {
    if (lane == 0) { g_ts[b * NJ + j - 1] = segEnd; g_c[b * NJ + j - 1] = 0.0f; }
    return;  // fallback path computed the full true chain already
  }

  float* base = lb + (size_t)b * TT * UU;
  const float TAU = 0.05f;

  float trueP = g_bound[((b << 4) + (j - 1)) * 64 + lane];  // prev boundary
  const float specInit = base[(size_t)jr * UU + cstoS];     // logits (pre-write)
  const float lgj = base[(size_t)jr * UU + tgtS];
  { float P = trueP; K2_FSTEP(jr, lgj); trueP = P; }        // row jr <- true-rel-ref
  float specP = specInit;

  float ring[4];
#pragma unroll
  for (int i = 0; i < 4; ++i) {
    int r = jr + 1 + i; if (r > segEnd) r = segEnd;
    ring[i] = base[(size_t)r * UU + cstoS];
  }
  int ts_rec = segEnd; float c_rec = 0.0f;
#pragma unroll 1
  for (int t = jr + 1; t <= segEnd; ++t) {
    const float specRow = ring[(t - (jr + 1)) & 3];
    const int pf = t + 4;
    if (pf <= segEnd) ring[(t - (jr + 1)) & 3] = base[(size_t)pf * UU + cstoS];
    const float Mt = k2_mcomb(trueP, tvS);
    const float Ms = k2_mcomb(specP, tvS);
    const float d = Mt - Ms;
    v2u s16d = __builtin_amdgcn_permlane16_swap(__float_as_uint(d),
                                                __float_as_uint(d), false, false);
    const float dx = m16sel ? __uint_as_float(s16d.x) : __uint_as_float(s16d.y);
    const float dsel = bit5v ? dx : d;
    const float nt = specRow + dsel;
    base[(size_t)t * UU + cstoS] = nt;
    const float dref = __uint_as_float(
        (unsigned)__builtin_amdgcn_readfirstlane(__float_as_int(d)));
    const bool uni = (__ballot(fabsf(d - dref) <= TAU) == ~0ull);
    trueP = nt;
    specP = specRow;
    if (uni) { ts_rec = t; c_rec = dref; break; }
  }
  if (lane == 0) { g_ts[b * NJ + j - 1] = ts_rec; g_c[b * NJ + j - 1] = c_rec; }
#else
  if (lane == 0) { g_ts[b * NJ + j - 1] = segEnd; g_c[b * NJ + j - 1] = 0.0f; }
#endif
}

// ---------------------------------------------------------------------------
// K3: backpointers; applies alpha offsets during the LDS load (row-uniform
// adds don't change the per-(t,u) argmax). off(row): jj=(row-1)>>SEGSH;
// jj==0 -> 0; else rows [jr,ts_jj] -> C[jj-1], (ts_jj, E_jj] -> C[jj].
// ---------------------------------------------------------------------------
__global__ __launch_bounds__(256) void k3_bp(const float* __restrict__ lb,
                                             const float* __restrict__ trans,
                                             const int* __restrict__ nwords,
                                             unsigned char* __restrict__ bp) {
  __shared__ float as[129 * 32];
  __shared__ float ts[32 * 32];
  const int b = blockIdx.x >> 4;
  const int c = blockIdx.x & 15;
  const int t0 = 128 * c;
  const int tid = threadIdx.x;
  const float* base = lb + (size_t)b * TT * UU;
  const int nw = nwords[b];

  float C[NSEG];
  int TS[NSEG];
  C[0] = 0.0f; TS[0] = 0;
#pragma unroll
  for (int j = 1; j <= NJ; ++j) {
    C[j] = C[j - 1] + g_c[b * NJ + j - 1];
    TS[j] = g_ts[b * NJ + j - 1];
  }

  for (int idx = tid; idx < 129 * 32; idx += 256) {
    const int gidx = (t0 - 1) * 32 + idx;
    float v = 0.0f;
    if (gidx >= 0 && gidx < TT * UU) {
      const int row = (t0 - 1) + (idx >> 5);
      const int jj = (row - 1) >> SEGSH;      // 0 for rows 0..SEGLEN
      float off = 0.0f;
      if (jj >= 1) off = (row <= TS[jj]) ? C[jj - 1] : C[jj];
      v = base[gidx] + off;
    }
    as[idx] = v;
  }
  for (int idx = tid; idx < 1024; idx += 256) ts[idx] = trans[idx];
  __syncthreads();

  const int u = tid & 31;
  const int tg = tid >> 5;
  unsigned char* bpu = bp + ((size_t)b * 32 + u) * TT;

#pragma unroll 1
  for (int qq = 0; qq < 4; ++qq) {
    const int tl0 = tg * 16 + qq * 4;
    unsigned int pack = 0;
#pragma unroll
    for (int e = 0; e < 4; ++e) {
      const int tl = tl0 + e;
      const int t = t0 + tl;
      int idx;
      if (t >= 1 && t < nw) {
        float m = as[tl * 32 + 0] + ts[0 * 32 + u];
        idx = 0;
#pragma unroll
        for (int v = 1; v < 32; ++v) {
          const float cv = as[tl * 32 + v] + ts[v * 32 + u];
          if (cv > m) { m = cv; idx = v; }
        }
      } else {
        idx = u;
      }
      pack |= ((unsigned int)idx) << (8 * e);
    }
    *(unsigned int*)(bpu + t0 + tl0) = pack;
  }
}

// ---------------------------------------------------------------------------
// K4: backtrace + best_score; applies off(nw-1) to its single alpha row read.
// ---------------------------------------------------------------------------
__global__ __launch_bounds__(64) void k4_backtrace(const float* __restrict__ lb,
                                                   const unsigned char* __restrict__ bp,
                                                   const int* __restrict__ nwords,
                                                   int* __restrict__ pred,
                                                   float* __restrict__ score) {
  const int b = blockIdx.x;
  const int lane = threadIdx.x;
  const int u = lane & 31;
  const int h = lane >> 5;
  const int nw = nwords[b];

  float off = 0.0f;
  {
    const int row = nw - 1;
    const int jj = (row - 1) >> SEGSH;
    if (jj >= 1) {
      float Cacc = 0.0f;
      float Cprev = 0.0f;
#pragma unroll
      for (int j = 1; j <= NJ; ++j) {
        Cprev = Cacc;
        Cacc += g_c[b * NJ + j - 1];
        if (j == jj) off = (row <= g_ts[b * NJ + j - 1]) ? Cprev : Cacc;
      }
    }
  }

  const float a = lb[((size_t)b * TT + (nw - 1)) * UU + u] + off;
  float m = a;
#pragma unroll
  for (int s = 32; s; s >>= 1) m = fmaxf(m, __shfl_xor(m, s));
  if (lane == 0) score[b] = m;
  const unsigned long long mask = __ballot(lane < 32 && a == m);
  int tag = __ffsll((unsigned long long)mask) - 1;
  tag = __builtin_amdgcn_readfirstlane(tag);

  int* predb = pred + b * TT;
  for (int p = nw - 1 + lane; p < TT; p += 64) predb[p] = tag;
  if (nw < 2) return;

  const unsigned char* bpb = bp + (size_t)b * 32 * TT;
  const int pcmax = (nw - 2) >> 6;
  const int thi_top = nw - 1;

  int wprev0 = 0;
  {
    const int toff = (pcmax + 1) * 64;
    if (toff < TT) wprev0 = *(const int*)(bpb + (size_t)u * TT + toff);
  }

  for (int pc = pcmax; pc >= 0; --pc) {
    int wreg[8];
#pragma unroll
    for (int j = 0; j < 8; ++j)
      wreg[j] = *(const int*)(bpb + (size_t)u * TT + pc * 64 + 4 * (h * 8 + j));
    int predv = 0;

    if (pc == pcmax) {
      const int thi = thi_top;
      if (pc * 64 + 64 <= thi) {
        const int val = __builtin_amdgcn_readlane(wprev0, tag);
        tag = __builtin_amdgcn_readfirstlane(val & 0xFF);
        if (lane == 63) predv = tag;
      }
#pragma unroll
      for (int lt = 63; lt >= 1; --lt) {
        if (pc * 64 + lt <= thi) {
          const int d = lt >> 2, byte = lt & 3;
          const int hs = d >> 3, j = d & 7;
          const int val = __builtin_amdgcn_readlane(wreg[j], hs * 32 + tag);
          tag = __builtin_amdgcn_readfirstlane((val >> (8 * byte)) & 0xFF);
          if (lane == lt - 1) predv = tag;
        }
      }
      const int lim = thi - pc * 64;
      if (lane < lim) predb[pc * 64 + lane] = predv;
    } else {
      {
        const int val = __builtin_amdgcn_readlane(wprev0, tag);
        tag = __builtin_amdgcn_readfirstlane(val & 0xFF);
        if (lane == 63) predv = tag;
      }
#pragma unroll
      for (int lt = 63; lt >= 1; --lt) {
        const int d = lt >> 2, byte = lt & 3;
        const int hs = d >> 3, j = d & 7;
        const int val = __builtin_amdgcn_readlane(wreg[j], hs * 32 + tag);
        tag = __builtin_amdgcn_readfirstlane((val >> (8 * byte)) & 0xFF);
        if (lane == lt - 1) predv = tag;
      }
      predb[pc * 64 + lane] = predv;
    }
    wprev0 = wreg[0];
  }
}

// ---------------------------------------------------------------------------
extern "C" void kernel_launch(void* const* d_in, const int* in_sizes, int n_in,
                              void* d_out, int out_size, void* d_ws, size_t ws_size,
                              hipStream_t stream) {
  const float* x = (const float*)d_in[0];
  const int* nwords = (const int*)d_in[1];
  const float* kern = (const float*)d_in[2];
  const float* chain = (const float*)d_in[3];
  const float* bias = (const float*)d_in[4];

  float* logits = (float*)d_ws;                                        // 16 MB
  unsigned char* bp = (unsigned char*)d_ws + (size_t)BB * TT * UU * 4; // +4 MB

  int* pred = (int*)d_out;
  float* score = (float*)d_out + (size_t)BB * TT;

  k1_logits<<<dim3(512), dim3(256), 0, stream>>>(x, kern, bias, logits);
  k2a_forward<<<dim3(NSEG * 64), dim3(64), 0, stream>>>(logits, chain);
  k2b_fixup<<<dim3(NJ * 64), dim3(64), 0, stream>>>(logits, chain);
  k3_bp<<<dim3(BB * 16), dim3(256), 0, stream>>>(logits, chain, nwords, bp);
  k4_backtrace<<<dim3(BB), dim3(64), 0, stream>>>(logits, bp, nwords, pred, score);
}